// Round 16
// baseline (37.574 us; speedup 1.0000x reference)
//
#include <hip/hip_runtime.h>
#include <hip/hip_bf16.h>

#define B_SZ   1024
#define NIN    64
#define NOUT   4096
#define NBATCH 64
#define NCONT  16
#define KTOT   96      // z(64) | cont(16) | zero-pad(16)
#define PCAP   48      // per-batch sample capacity (Poisson(16) max ~32)

#define WTB_UNITS  (256 * 3 * 64)             // 49152 16B-units
#define XT_ELEMS   (B_SZ * KTOT)              // 98304
#define WTB_BLOCKS (WTB_UNITS / 256)          // 192
#define XT_BLOCKS  (XT_ELEMS / 256)           // 384

typedef __attribute__((ext_vector_type(8))) short short8;   // 8 bf16 = 4 VGPR
typedef __attribute__((ext_vector_type(4))) float f32x4;

// f32 -> bf16 bits, round-to-nearest-even
__device__ __forceinline__ short f2bf(float f) {
    unsigned u = __float_as_uint(f);
    return (short)((u + 0x7FFFu + ((u >> 16) & 1u)) >> 16);
}
// pack 8 f32 (two float4) -> short8 bf16 in order
__device__ __forceinline__ short8 pk8(float4 a, float4 b) {
    short8 r;
    r[0]=f2bf(a.x); r[1]=f2bf(a.y); r[2]=f2bf(a.z); r[3]=f2bf(a.w);
    r[4]=f2bf(b.x); r[5]=f2bf(b.y); r[6]=f2bf(b.z); r[7]=f2bf(b.w);
    return r;
}
// K-permutation (applied to BOTH operands -> GEMM invariant)
__device__ __forceinline__ int kpi(int kq, int j) {
    return (j < 4) ? (kq * 4 + j) : (16 + kq * 4 + (j - 4));
}

// ---------------------------------------------------------------------------
// Prep (unchanged from R13, which passed).
// ---------------------------------------------------------------------------
__global__ __launch_bounds__(256) void k_prep(
    const float* __restrict__ z, const int* __restrict__ idx,
    const float* __restrict__ cont, const float* __restrict__ amat_W,
    const float* __restrict__ cont_W,
    int* __restrict__ cnt_ws, int* __restrict__ perm_ws,
    unsigned short* __restrict__ Xt, unsigned short* __restrict__ Wtb)
{
    const int bid = blockIdx.x, tid = threadIdx.x;

    if (bid < WTB_BLOCKS) {
        const int u   = bid * 256 + tid;
        const int nt  = u / 192, rem = u - nt * 192;
        const int ks  = rem >> 6, lane = rem & 63;
        const int kq  = lane >> 4, nl = lane & 15;
        const int n   = nt * 16 + nl;
        unsigned short v8[8];
        #pragma unroll
        for (int j = 0; j < 8; ++j) {
            const int k = ks * 32 + kpi(kq, j);
            float v = 0.f;
            if (k < NIN)              v = amat_W[k * NOUT + n];
            else if (k < NIN + NCONT) v = cont_W[(k - NIN) * NOUT + n];
            v8[j] = (unsigned short)f2bf(v);
        }
        *(int4*)(Wtb + (size_t)u * 8) = *(int4*)v8;       // 16B coalesced
    } else if (bid < WTB_BLOCKS + XT_BLOCKS) {
        const int i = (bid - WTB_BLOCKS) * 256 + tid;
        const int c = i / KTOT, k = i - c * KTOT;
        float v = 0.f;
        if (k < NIN)              v = z[c * NIN + k];
        else if (k < NIN + NCONT) v = cont[c * NCONT + (k - NIN)];
        Xt[i] = (unsigned short)f2bf(v);
    } else {                                  // perm / cnt (one block)
        __shared__ int lcnt[NBATCH];
        if (tid < NBATCH) lcnt[tid] = 0;
        for (int i = tid; i < NBATCH * PCAP; i += 256) perm_ws[i] = 0;
        __syncthreads();
        for (int c = tid; c < B_SZ; c += 256) {
            const int b = idx[c];
            const int p = atomicAdd(&lcnt[b], 1);
            if (p < PCAP) perm_ws[b * PCAP + p] = c;
        }
        __syncthreads();
        if (tid < NBATCH) cnt_ws[tid] = min(lcnt[tid], PCAP);
    }
}

// ---------------------------------------------------------------------------
// Xa: A-fragments pre-gathered per (batch, m-tile, ks), pi-permuted
// (unchanged from R13).
// ---------------------------------------------------------------------------
__global__ __launch_bounds__(256) void k_xa(
    const unsigned short* __restrict__ Xt, const int* __restrict__ perm_ws,
    unsigned short* __restrict__ Xa)
{
    const int t = blockIdx.x * 256 + threadIdx.x;
    const int u = t >> 6, lane = t & 63;
    const int b = u / 9, r = u - b * 9;
    const int mt = r / 3, ks = r - mt * 3;
    const int kq = lane >> 4, ml = lane & 15;
    const int c = perm_ws[b * PCAP + mt * 16 + ml];
    const unsigned short* s0 = Xt + c * KTOT + ks * 32 + kq * 4;
    ushort4 lo = *(const ushort4*)s0;
    ushort4 hi = *(const ushort4*)(s0 + 16);
    unsigned short v8[8] = {lo.x, lo.y, lo.z, lo.w, hi.x, hi.y, hi.z, hi.w};
    *(int4*)(Xa + (size_t)u * 512 + lane * 8) = *(int4*)v8;
}

// ---------------------------------------------------------------------------
// Main GEMM — 2 n-tiles per wave, ONE self-contained asm block.
// R14/R15 lesson: loads and their waitcnt MUST live in the same asm block
// (asm outputs are modeled as valid at block end; regalloc may copy/spill
// in-flight dest registers between blocks -> garbage store addresses ->
// R15's core dump). R12/R13's within-block pattern is safe by construction.
// This round keeps that pattern and amortizes: 22 loads serve 2 tiles
// (11/tile vs R13's 19), waves halve to 8192. Signed offset biasing (mid
// bases, tile stride 4096 > 4095 imm) gives both tiles one address VGPR.
// ---------------------------------------------------------------------------
__global__ __launch_bounds__(64) void k_gemm(
    const float* __restrict__ embed_A,
    const float* __restrict__ embed_h3,
    const unsigned short* __restrict__ Xa,
    const unsigned short* __restrict__ Wtb,
    const int* __restrict__ cnt_ws,
    const int* __restrict__ perm_ws,
    float* __restrict__ out)
{
    const int lane = threadIdx.x;
    const int nl = lane & 15, kq = lane >> 4;
    const int ib = blockIdx.x;                    // 0..127
    const int b  = blockIdx.y;                    // 0..63
    const int cnt = cnt_ws[b];                    // wave-uniform
    if (cnt == 0) return;
    const int ntiles = (cnt + 15) >> 4;
    const int t0 = ib * 2;                        // first n-tile (0..254)
    const int na = t0 * 16 + nl;                  // tile0 n
    const int nb2 = na + 16;                      // tile1 n

    // C++ loads (compiler-managed waits; issued before asm, drained by our
    // vmcnt(0) -> compiler's later waits are free)
    const float h3a = embed_h3[b * NOUT + na];
    const float h3b = embed_h3[b * NOUT + nb2];

    const unsigned oxa0 = (unsigned)(b * 9216 + lane * 16);
    const unsigned oxa1 = oxa0 + 3072;
    const unsigned opv  = (unsigned)(b * (PCAP * 4) + kq * 16);
    const unsigned oem  = (unsigned)((unsigned)(b * NOUT + na) * 256
                                     + kq * 16 + 2048);
    const unsigned owm  = (unsigned)(t0 * 3072 + lane * 16 + 1536);

    int4 A00, A01, A02, A10, A11, A12, PV0, PV1;
    int4 EA0, EA1, EA2, EA3, EB0, EB1, EB2, EB3;
    int4 WA0, WA1, WA2, WB0, WB1, WB2;
    asm volatile(
        "global_load_dwordx4 %[a00], %[oxa0], %[xq]\n\t"
        "global_load_dwordx4 %[a01], %[oxa0], %[xq] offset:1024\n\t"
        "global_load_dwordx4 %[a02], %[oxa0], %[xq] offset:2048\n\t"
        "global_load_dwordx4 %[a10], %[oxa1], %[xq]\n\t"
        "global_load_dwordx4 %[a11], %[oxa1], %[xq] offset:1024\n\t"
        "global_load_dwordx4 %[a12], %[oxa1], %[xq] offset:2048\n\t"
        "global_load_dwordx4 %[pv0], %[opv], %[pm]\n\t"
        "global_load_dwordx4 %[pv1], %[opv], %[pm] offset:64\n\t"
        "global_load_dwordx4 %[ea0], %[oem], %[ep] offset:-2048\n\t"
        "global_load_dwordx4 %[ea1], %[oem], %[ep] offset:-1984\n\t"
        "global_load_dwordx4 %[ea2], %[oem], %[ep] offset:-1920\n\t"
        "global_load_dwordx4 %[ea3], %[oem], %[ep] offset:-1856\n\t"
        "global_load_dwordx4 %[eb0], %[oem], %[ep] offset:2048\n\t"
        "global_load_dwordx4 %[eb1], %[oem], %[ep] offset:2112\n\t"
        "global_load_dwordx4 %[eb2], %[oem], %[ep] offset:2176\n\t"
        "global_load_dwordx4 %[eb3], %[oem], %[ep] offset:2240\n\t"
        "global_load_dwordx4 %[wa0], %[owm], %[wq] offset:-1536\n\t"
        "global_load_dwordx4 %[wa1], %[owm], %[wq] offset:-512\n\t"
        "global_load_dwordx4 %[wa2], %[owm], %[wq] offset:512\n\t"
        "global_load_dwordx4 %[wb0], %[owm], %[wq] offset:1536\n\t"
        "global_load_dwordx4 %[wb1], %[owm], %[wq] offset:2560\n\t"
        "global_load_dwordx4 %[wb2], %[owm], %[wq] offset:3584\n\t"
        "s_waitcnt vmcnt(0)"
        : [a00]"=&v"(A00), [a01]"=&v"(A01), [a02]"=&v"(A02),
          [a10]"=&v"(A10), [a11]"=&v"(A11), [a12]"=&v"(A12),
          [pv0]"=&v"(PV0), [pv1]"=&v"(PV1),
          [ea0]"=&v"(EA0), [ea1]"=&v"(EA1), [ea2]"=&v"(EA2), [ea3]"=&v"(EA3),
          [eb0]"=&v"(EB0), [eb1]"=&v"(EB1), [eb2]"=&v"(EB2), [eb3]"=&v"(EB3),
          [wa0]"=&v"(WA0), [wa1]"=&v"(WA1), [wa2]"=&v"(WA2),
          [wb0]"=&v"(WB0), [wb1]"=&v"(WB1), [wb2]"=&v"(WB2)
        : [oxa0]"v"(oxa0), [oxa1]"v"(oxa1), [opv]"v"(opv),
          [oem]"v"(oem), [owm]"v"(owm),
          [xq]"s"(Xa), [pm]"s"(perm_ws), [ep]"s"(embed_A), [wq]"s"(Wtb)
        : "memory");
    __builtin_amdgcn_sched_barrier(0);            // rule-#18 fence

    const short8 az00 = *(const short8*)&A00;
    const short8 az01 = *(const short8*)&A01;
    const short8 az02 = *(const short8*)&A02;
    const short8 az10 = *(const short8*)&A10;
    const short8 az11 = *(const short8*)&A11;
    const short8 az12 = *(const short8*)&A12;

    // ---- tile 0 -------------------------------------------------------------
    {
        const short8 eb0 = pk8(*(const float4*)&EA0, *(const float4*)&EA1);
        const short8 eb1 = pk8(*(const float4*)&EA2, *(const float4*)&EA3);
        const short8 wt0 = *(const short8*)&WA0;
        const short8 wt1 = *(const short8*)&WA1;
        const short8 wt2 = *(const short8*)&WA2;
        {
            f32x4 acc = {0, 0, 0, 0};
            acc = __builtin_amdgcn_mfma_f32_16x16x32_bf16(az00, eb0, acc, 0, 0, 0);
            acc = __builtin_amdgcn_mfma_f32_16x16x32_bf16(az01, eb1, acc, 0, 0, 0);
            acc = __builtin_amdgcn_mfma_f32_16x16x32_bf16(az00, wt0, acc, 0, 0, 0);
            acc = __builtin_amdgcn_mfma_f32_16x16x32_bf16(az01, wt1, acc, 0, 0, 0);
            acc = __builtin_amdgcn_mfma_f32_16x16x32_bf16(az02, wt2, acc, 0, 0, 0);
            const int sb = kq * 4;
            if (sb + 0 < cnt) out[(size_t)PV0.x * NOUT + na] = acc[0] + h3a;
            if (sb + 1 < cnt) out[(size_t)PV0.y * NOUT + na] = acc[1] + h3a;
            if (sb + 2 < cnt) out[(size_t)PV0.z * NOUT + na] = acc[2] + h3a;
            if (sb + 3 < cnt) out[(size_t)PV0.w * NOUT + na] = acc[3] + h3a;
        }
        if (ntiles > 1) {
            f32x4 acc = {0, 0, 0, 0};
            acc = __builtin_amdgcn_mfma_f32_16x16x32_bf16(az10, eb0, acc, 0, 0, 0);
            acc = __builtin_amdgcn_mfma_f32_16x16x32_bf16(az11, eb1, acc, 0, 0, 0);
            acc = __builtin_amdgcn_mfma_f32_16x16x32_bf16(az10, wt0, acc, 0, 0, 0);
            acc = __builtin_amdgcn_mfma_f32_16x16x32_bf16(az11, wt1, acc, 0, 0, 0);
            acc = __builtin_amdgcn_mfma_f32_16x16x32_bf16(az12, wt2, acc, 0, 0, 0);
            const int sb = 16 + kq * 4;
            if (sb + 0 < cnt) out[(size_t)PV1.x * NOUT + na] = acc[0] + h3a;
            if (sb + 1 < cnt) out[(size_t)PV1.y * NOUT + na] = acc[1] + h3a;
            if (sb + 2 < cnt) out[(size_t)PV1.z * NOUT + na] = acc[2] + h3a;
            if (sb + 3 < cnt) out[(size_t)PV1.w * NOUT + na] = acc[3] + h3a;
        }
    }
    // ---- tile 1 -------------------------------------------------------------
    {
        const short8 eb0 = pk8(*(const float4*)&EB0, *(const float4*)&EB1);
        const short8 eb1 = pk8(*(const float4*)&EB2, *(const float4*)&EB3);
        const short8 wt0 = *(const short8*)&WB0;
        const short8 wt1 = *(const short8*)&WB1;
        const short8 wt2 = *(const short8*)&WB2;
        {
            f32x4 acc = {0, 0, 0, 0};
            acc = __builtin_amdgcn_mfma_f32_16x16x32_bf16(az00, eb0, acc, 0, 0, 0);
            acc = __builtin_amdgcn_mfma_f32_16x16x32_bf16(az01, eb1, acc, 0, 0, 0);
            acc = __builtin_amdgcn_mfma_f32_16x16x32_bf16(az00, wt0, acc, 0, 0, 0);
            acc = __builtin_amdgcn_mfma_f32_16x16x32_bf16(az01, wt1, acc, 0, 0, 0);
            acc = __builtin_amdgcn_mfma_f32_16x16x32_bf16(az02, wt2, acc, 0, 0, 0);
            const int sb = kq * 4;
            if (sb + 0 < cnt) out[(size_t)PV0.x * NOUT + nb2] = acc[0] + h3b;
            if (sb + 1 < cnt) out[(size_t)PV0.y * NOUT + nb2] = acc[1] + h3b;
            if (sb + 2 < cnt) out[(size_t)PV0.z * NOUT + nb2] = acc[2] + h3b;
            if (sb + 3 < cnt) out[(size_t)PV0.w * NOUT + nb2] = acc[3] + h3b;
        }
        if (ntiles > 1) {
            f32x4 acc = {0, 0, 0, 0};
            acc = __builtin_amdgcn_mfma_f32_16x16x32_bf16(az10, eb0, acc, 0, 0, 0);
            acc = __builtin_amdgcn_mfma_f32_16x16x32_bf16(az11, eb1, acc, 0, 0, 0);
            acc = __builtin_amdgcn_mfma_f32_16x16x32_bf16(az10, wt0, acc, 0, 0, 0);
            acc = __builtin_amdgcn_mfma_f32_16x16x32_bf16(az11, wt1, acc, 0, 0, 0);
            acc = __builtin_amdgcn_mfma_f32_16x16x32_bf16(az12, wt2, acc, 0, 0, 0);
            const int sb = 16 + kq * 4;
            if (sb + 0 < cnt) out[(size_t)PV1.x * NOUT + nb2] = acc[0] + h3b;
            if (sb + 1 < cnt) out[(size_t)PV1.y * NOUT + nb2] = acc[1] + h3b;
            if (sb + 2 < cnt) out[(size_t)PV1.z * NOUT + nb2] = acc[2] + h3b;
            if (sb + 3 < cnt) out[(size_t)PV1.w * NOUT + nb2] = acc[3] + h3b;
        }
    }
    // ---- rare third m-tile (cnt>32): plain C++ loads (compiler-safe) -------
    if (ntiles > 2) {
        const unsigned short* xa2 = Xa + ((size_t)(b * 9 + 6)) * 512 + lane * 8;
        const short8 az20 = *(const short8*)(xa2);
        const short8 az21 = *(const short8*)(xa2 + 512);
        const short8 az22 = *(const short8*)(xa2 + 1024);
        const int4 pv2 = *(const int4*)(perm_ws + b * PCAP + 32 + kq * 4);
        const int sb = 32 + kq * 4;
        {
            const short8 eb0 = pk8(*(const float4*)&EA0, *(const float4*)&EA1);
            const short8 eb1 = pk8(*(const float4*)&EA2, *(const float4*)&EA3);
            f32x4 acc = {0, 0, 0, 0};
            acc = __builtin_amdgcn_mfma_f32_16x16x32_bf16(az20, eb0, acc, 0, 0, 0);
            acc = __builtin_amdgcn_mfma_f32_16x16x32_bf16(az21, eb1, acc, 0, 0, 0);
            acc = __builtin_amdgcn_mfma_f32_16x16x32_bf16(az20, *(const short8*)&WA0, acc, 0, 0, 0);
            acc = __builtin_amdgcn_mfma_f32_16x16x32_bf16(az21, *(const short8*)&WA1, acc, 0, 0, 0);
            acc = __builtin_amdgcn_mfma_f32_16x16x32_bf16(az22, *(const short8*)&WA2, acc, 0, 0, 0);
            if (sb + 0 < cnt) out[(size_t)pv2.x * NOUT + na] = acc[0] + h3a;
            if (sb + 1 < cnt) out[(size_t)pv2.y * NOUT + na] = acc[1] + h3a;
            if (sb + 2 < cnt) out[(size_t)pv2.z * NOUT + na] = acc[2] + h3a;
            if (sb + 3 < cnt) out[(size_t)pv2.w * NOUT + na] = acc[3] + h3a;
        }
        {
            const short8 eb0 = pk8(*(const float4*)&EB0, *(const float4*)&EB1);
            const short8 eb1 = pk8(*(const float4*)&EB2, *(const float4*)&EB3);
            f32x4 acc = {0, 0, 0, 0};
            acc = __builtin_amdgcn_mfma_f32_16x16x32_bf16(az20, eb0, acc, 0, 0, 0);
            acc = __builtin_amdgcn_mfma_f32_16x16x32_bf16(az21, eb1, acc, 0, 0, 0);
            acc = __builtin_amdgcn_mfma_f32_16x16x32_bf16(az20, *(const short8*)&WB0, acc, 0, 0, 0);
            acc = __builtin_amdgcn_mfma_f32_16x16x32_bf16(az21, *(const short8*)&WB1, acc, 0, 0, 0);
            acc = __builtin_amdgcn_mfma_f32_16x16x32_bf16(az22, *(const short8*)&WB2, acc, 0, 0, 0);
            if (sb + 0 < cnt) out[(size_t)pv2.x * NOUT + nb2] = acc[0] + h3b;
            if (sb + 1 < cnt) out[(size_t)pv2.y * NOUT + nb2] = acc[1] + h3b;
            if (sb + 2 < cnt) out[(size_t)pv2.z * NOUT + nb2] = acc[2] + h3b;
            if (sb + 3 < cnt) out[(size_t)pv2.w * NOUT + nb2] = acc[3] + h3b;
        }
    }
}

// ---------------------------------------------------------------------------
// Softmax: in-place row softmax * size_factor; blocks 0..15 also write
// inverse_dispersion = exp(px_r).
// ---------------------------------------------------------------------------
__global__ __launch_bounds__(256) void k_softmax(
    float*       __restrict__ out,
    const float* __restrict__ sf,
    const float* __restrict__ px_r)
{
    const int c   = blockIdx.x;
    const int tid = threadIdx.x;
    float4* row4 = reinterpret_cast<float4*>(out + (size_t)c * NOUT);

    float4 v[4];
    #pragma unroll
    for (int j = 0; j < 4; ++j) v[j] = row4[j * 256 + tid];

    float m = -3.4e38f;
    #pragma unroll
    for (int j = 0; j < 4; ++j)
        m = fmaxf(fmaxf(fmaxf(m, v[j].x), fmaxf(v[j].y, v[j].z)), v[j].w);

    #pragma unroll
    for (int off = 32; off > 0; off >>= 1)
        m = fmaxf(m, __shfl_xor(m, off, 64));

    __shared__ float s_red[8];
    const int wave = tid >> 6;
    const int lane = tid & 63;
    if (lane == 0) s_red[wave] = m;
    __syncthreads();
    m = fmaxf(fmaxf(s_red[0], s_red[1]), fmaxf(s_red[2], s_red[3]));

    float s = 0.f;
    #pragma unroll
    for (int j = 0; j < 4; ++j) {
        v[j].x = __expf(v[j].x - m); v[j].y = __expf(v[j].y - m);
        v[j].z = __expf(v[j].z - m); v[j].w = __expf(v[j].w - m);
        s += v[j].x + v[j].y + v[j].z + v[j].w;
    }
    #pragma unroll
    for (int off = 32; off > 0; off >>= 1)
        s += __shfl_xor(s, off, 64);
    if (lane == 0) s_red[4 + wave] = s;
    __syncthreads();
    s = s_red[4] + s_red[5] + s_red[6] + s_red[7];

    const float scale = sf[c] / s;
    #pragma unroll
    for (int j = 0; j < 4; ++j) {
        v[j].x *= scale; v[j].y *= scale; v[j].z *= scale; v[j].w *= scale;
        row4[j * 256 + tid] = v[j];
    }

    if (c < NOUT / 256) {                 // 16 blocks cover px_r
        const int i = c * 256 + tid;
        out[(size_t)B_SZ * NOUT + i] = __expf(px_r[i]);
    }
}

// ---------------------------------------------------------------------------
extern "C" void kernel_launch(void* const* d_in, const int* in_sizes, int n_in,
                              void* d_out, int out_size, void* d_ws, size_t ws_size,
                              hipStream_t stream)
{
    const float* z       = (const float*)d_in[0];
    const int*   idx     = (const int*)  d_in[1];
    const float* sf      = (const float*)d_in[2];
    const float* cont    = (const float*)d_in[3];
    const float* amat_W  = (const float*)d_in[4];
    const float* embed_A = (const float*)d_in[5];
    const float* eh3     = (const float*)d_in[6];
    const float* cont_W  = (const float*)d_in[7];
    const float* px_r    = (const float*)d_in[8];
    float* out = (float*)d_out;

    // ws (bytes): cnt[64]@0 | perm[64*48]@256 | Xt bf16 @16384 (196608)
    //             | Wtb bf16 @212992 (786432) | Xa bf16 @999424 (589824)
    char* ws = (char*)d_ws;
    int*            cnt_ws  = (int*)ws;
    int*            perm_ws = (int*)(ws + 256);
    unsigned short* Xt      = (unsigned short*)(ws + 16384);
    unsigned short* Wtb     = (unsigned short*)(ws + 212992);
    unsigned short* Xa      = (unsigned short*)(ws + 999424);

    k_prep<<<WTB_BLOCKS + XT_BLOCKS + 1, 256, 0, stream>>>(
        z, idx, cont, amat_W, cont_W, cnt_ws, perm_ws, Xt, Wtb);

    k_xa<<<144, 256, 0, stream>>>(Xt, perm_ws, Xa);

    dim3 grid1(128, NBATCH);              // 8192 waves x 2 tiles each
    k_gemm<<<grid1, 64, 0, stream>>>(embed_A, eh3, Xa, Wtb,
                                     cnt_ws, perm_ws, out);

    k_softmax<<<B_SZ, 256, 0, stream>>>(out, sf, px_r);
}

// Round 17
// 36.258 us; speedup vs baseline: 1.0363x; 1.0363x over previous
//
#include <hip/hip_runtime.h>
#include <hip/hip_bf16.h>

#define B_SZ   1024
#define NIN    64
#define NOUT   4096
#define NBATCH 64
#define NCONT  16
#define KTOT   96      // z(64) | cont(16) | zero-pad(16)
#define PCAP   48      // per-batch sample capacity (Poisson(16) max ~32)

#define WTB_UNITS  (256 * 3 * 64)             // 49152 16B-units
#define XT_ELEMS   (B_SZ * KTOT)              // 98304
#define WTB_BLOCKS (WTB_UNITS / 256)          // 192
#define XT_BLOCKS  (XT_ELEMS / 256)           // 384

typedef __attribute__((ext_vector_type(8))) short short8;   // 8 bf16 = 4 VGPR
typedef __attribute__((ext_vector_type(4))) float f32x4;

// f32 -> bf16 bits, round-to-nearest-even
__device__ __forceinline__ short f2bf(float f) {
    unsigned u = __float_as_uint(f);
    return (short)((u + 0x7FFFu + ((u >> 16) & 1u)) >> 16);
}
// pack 8 f32 (two float4) -> short8 bf16 in order
__device__ __forceinline__ short8 pk8(float4 a, float4 b) {
    short8 r;
    r[0]=f2bf(a.x); r[1]=f2bf(a.y); r[2]=f2bf(a.z); r[3]=f2bf(a.w);
    r[4]=f2bf(b.x); r[5]=f2bf(b.y); r[6]=f2bf(b.z); r[7]=f2bf(b.w);
    return r;
}
// K-permutation (applied to BOTH operands -> GEMM invariant)
__device__ __forceinline__ int kpi(int kq, int j) {
    return (j < 4) ? (kq * 4 + j) : (16 + kq * 4 + (j - 4));
}

// ---------------------------------------------------------------------------
// Prep (unchanged from R13/R16, passing).
// ---------------------------------------------------------------------------
__global__ __launch_bounds__(256) void k_prep(
    const float* __restrict__ z, const int* __restrict__ idx,
    const float* __restrict__ cont, const float* __restrict__ amat_W,
    const float* __restrict__ cont_W,
    int* __restrict__ cnt_ws, int* __restrict__ perm_ws,
    unsigned short* __restrict__ Xt, unsigned short* __restrict__ Wtb)
{
    const int bid = blockIdx.x, tid = threadIdx.x;

    if (bid < WTB_BLOCKS) {
        const int u   = bid * 256 + tid;
        const int nt  = u / 192, rem = u - nt * 192;
        const int ks  = rem >> 6, lane = rem & 63;
        const int kq  = lane >> 4, nl = lane & 15;
        const int n   = nt * 16 + nl;
        unsigned short v8[8];
        #pragma unroll
        for (int j = 0; j < 8; ++j) {
            const int k = ks * 32 + kpi(kq, j);
            float v = 0.f;
            if (k < NIN)              v = amat_W[k * NOUT + n];
            else if (k < NIN + NCONT) v = cont_W[(k - NIN) * NOUT + n];
            v8[j] = (unsigned short)f2bf(v);
        }
        *(int4*)(Wtb + (size_t)u * 8) = *(int4*)v8;       // 16B coalesced
    } else if (bid < WTB_BLOCKS + XT_BLOCKS) {
        const int i = (bid - WTB_BLOCKS) * 256 + tid;
        const int c = i / KTOT, k = i - c * KTOT;
        float v = 0.f;
        if (k < NIN)              v = z[c * NIN + k];
        else if (k < NIN + NCONT) v = cont[c * NCONT + (k - NIN)];
        Xt[i] = (unsigned short)f2bf(v);
    } else {                                  // perm / cnt (one block)
        __shared__ int lcnt[NBATCH];
        if (tid < NBATCH) lcnt[tid] = 0;
        for (int i = tid; i < NBATCH * PCAP; i += 256) perm_ws[i] = 0;
        __syncthreads();
        for (int c = tid; c < B_SZ; c += 256) {
            const int b = idx[c];
            const int p = atomicAdd(&lcnt[b], 1);
            if (p < PCAP) perm_ws[b * PCAP + p] = c;
        }
        __syncthreads();
        if (tid < NBATCH) cnt_ws[tid] = min(lcnt[tid], PCAP);
    }
}

// ---------------------------------------------------------------------------
// Xa: A-fragments pre-gathered per (batch, m-tile, ks), pi-permuted
// (unchanged from R13).
// ---------------------------------------------------------------------------
__global__ __launch_bounds__(256) void k_xa(
    const unsigned short* __restrict__ Xt, const int* __restrict__ perm_ws,
    unsigned short* __restrict__ Xa)
{
    const int t = blockIdx.x * 256 + threadIdx.x;
    const int u = t >> 6, lane = t & 63;
    const int b = u / 9, r = u - b * 9;
    const int mt = r / 3, ks = r - mt * 3;
    const int kq = lane >> 4, ml = lane & 15;
    const int c = perm_ws[b * PCAP + mt * 16 + ml];
    const unsigned short* s0 = Xt + c * KTOT + ks * 32 + kq * 4;
    ushort4 lo = *(const ushort4*)s0;
    ushort4 hi = *(const ushort4*)(s0 + 16);
    unsigned short v8[8] = {lo.x, lo.y, lo.z, lo.w, hi.x, hi.y, hi.z, hi.w};
    *(int4*)(Xa + (size_t)u * 512 + lane * 8) = *(int4*)v8;
}

// ---------------------------------------------------------------------------
// Main GEMM — 4 n-tiles per wave, Xa/pv amortized.
// R13/R16 traffic audit: ~224MB of L2/L3 traffic in 29us (~8 TB/s) - the
// fabric/L3 was the limiter, and 96MB of it was Xa re-reads + 48MB Wtb
// re-reads (embed streaming evicts them from the 4MB per-XCD L2). This
// version: wave owns 4 consecutive n-tiles of one batch; Xa+pv loaded ONCE
// (prologue asm block, own vmcnt(0)); each iteration is a self-contained
// asm block (8 loads + vmcnt(0)) - loads and waits NEVER split across
// blocks (R15 crash lesson). Traffic 224 -> ~153MB.
// ---------------------------------------------------------------------------
__global__ __launch_bounds__(64) void k_gemm(
    const float* __restrict__ embed_A,
    const float* __restrict__ embed_h3,
    const unsigned short* __restrict__ Xa,
    const unsigned short* __restrict__ Wtb,
    const int* __restrict__ cnt_ws,
    const int* __restrict__ perm_ws,
    float* __restrict__ out)
{
    const int lane = threadIdx.x;
    const int nl = lane & 15, kq = lane >> 4;
    const int ib = blockIdx.x;                    // 0..63
    const int b  = blockIdx.y;                    // 0..63
    const int cnt = cnt_ws[b];                    // wave-uniform
    if (cnt == 0) return;
    const int ntiles = (cnt + 15) >> 4;
    const int t0 = ib * 4;                        // first n-tile

    const unsigned oxa0 = (unsigned)(b * 9216 + lane * 16);
    const unsigned oxa1 = oxa0 + 3072;
    const unsigned opv  = (unsigned)(b * (PCAP * 4) + kq * 16);
    const unsigned oe0  = (unsigned)((unsigned)(b * NOUT + t0 * 16 + nl) * 256
                                     + kq * 16);
    const unsigned ow0  = (unsigned)(t0 * 3072 + lane * 16);
    const unsigned oh0  = (unsigned)((b * NOUT + t0 * 16 + nl) * 4);

    // ---- prologue: Xa + pv, once per wave (self-contained block) -----------
    int4 A00, A01, A02, A10, A11, A12, PV0, PV1;
    asm volatile(
        "global_load_dwordx4 %[a00], %[oxa0], %[xq]\n\t"
        "global_load_dwordx4 %[a01], %[oxa0], %[xq] offset:1024\n\t"
        "global_load_dwordx4 %[a02], %[oxa0], %[xq] offset:2048\n\t"
        "global_load_dwordx4 %[a10], %[oxa1], %[xq]\n\t"
        "global_load_dwordx4 %[a11], %[oxa1], %[xq] offset:1024\n\t"
        "global_load_dwordx4 %[a12], %[oxa1], %[xq] offset:2048\n\t"
        "global_load_dwordx4 %[pv0], %[opv], %[pm]\n\t"
        "global_load_dwordx4 %[pv1], %[opv], %[pm] offset:64\n\t"
        "s_waitcnt vmcnt(0)"
        : [a00]"=&v"(A00), [a01]"=&v"(A01), [a02]"=&v"(A02),
          [a10]"=&v"(A10), [a11]"=&v"(A11), [a12]"=&v"(A12),
          [pv0]"=&v"(PV0), [pv1]"=&v"(PV1)
        : [oxa0]"v"(oxa0), [oxa1]"v"(oxa1), [opv]"v"(opv),
          [xq]"s"(Xa), [pm]"s"(perm_ws)
        : "memory");
    __builtin_amdgcn_sched_barrier(0);

    const short8 az00 = *(const short8*)&A00;
    const short8 az01 = *(const short8*)&A01;
    const short8 az02 = *(const short8*)&A02;
    const short8 az10 = *(const short8*)&A10;
    const short8 az11 = *(const short8*)&A11;
    const short8 az12 = *(const short8*)&A12;

    #pragma unroll
    for (int it = 0; it < 4; ++it) {
        const unsigned oe = oe0 + (unsigned)(it * 4096);
        const unsigned ow = ow0 + (unsigned)(it * 3072);
        const unsigned oh = oh0 + (unsigned)(it * 64);
        const int n = (t0 + it) * 16 + nl;

        int4 E0, E1, E2, E3, W0, W1, W2;
        float H3;
        asm volatile(
            "global_load_dwordx4 %[e0], %[oe], %[ep]\n\t"
            "global_load_dwordx4 %[e1], %[oe], %[ep] offset:64\n\t"
            "global_load_dwordx4 %[e2], %[oe], %[ep] offset:128\n\t"
            "global_load_dwordx4 %[e3], %[oe], %[ep] offset:192\n\t"
            "global_load_dwordx4 %[w0], %[ow], %[wq]\n\t"
            "global_load_dwordx4 %[w1], %[ow], %[wq] offset:1024\n\t"
            "global_load_dwordx4 %[w2], %[ow], %[wq] offset:2048\n\t"
            "global_load_dword   %[h],  %[oh], %[hp]\n\t"
            "s_waitcnt vmcnt(0)"
            : [e0]"=&v"(E0), [e1]"=&v"(E1), [e2]"=&v"(E2), [e3]"=&v"(E3),
              [w0]"=&v"(W0), [w1]"=&v"(W1), [w2]"=&v"(W2), [h]"=&v"(H3)
            : [oe]"v"(oe), [ow]"v"(ow), [oh]"v"(oh),
              [ep]"s"(embed_A), [wq]"s"(Wtb), [hp]"s"(embed_h3)
            : "memory");
        __builtin_amdgcn_sched_barrier(0);        // rule-#18 fence

        const short8 eb0 = pk8(*(const float4*)&E0, *(const float4*)&E1);
        const short8 eb1 = pk8(*(const float4*)&E2, *(const float4*)&E3);
        const short8 wt0 = *(const short8*)&W0;
        const short8 wt1 = *(const short8*)&W1;
        const short8 wt2 = *(const short8*)&W2;

        {   // m-tile 0
            f32x4 acc = {0, 0, 0, 0};
            acc = __builtin_amdgcn_mfma_f32_16x16x32_bf16(az00, eb0, acc, 0, 0, 0);
            acc = __builtin_amdgcn_mfma_f32_16x16x32_bf16(az01, eb1, acc, 0, 0, 0);
            acc = __builtin_amdgcn_mfma_f32_16x16x32_bf16(az00, wt0, acc, 0, 0, 0);
            acc = __builtin_amdgcn_mfma_f32_16x16x32_bf16(az01, wt1, acc, 0, 0, 0);
            acc = __builtin_amdgcn_mfma_f32_16x16x32_bf16(az02, wt2, acc, 0, 0, 0);
            const int sb = kq * 4;
            if (sb + 0 < cnt) out[(size_t)PV0.x * NOUT + n] = acc[0] + H3;
            if (sb + 1 < cnt) out[(size_t)PV0.y * NOUT + n] = acc[1] + H3;
            if (sb + 2 < cnt) out[(size_t)PV0.z * NOUT + n] = acc[2] + H3;
            if (sb + 3 < cnt) out[(size_t)PV0.w * NOUT + n] = acc[3] + H3;
        }
        if (ntiles > 1) {                         // m-tile 1 (uniform branch)
            f32x4 acc = {0, 0, 0, 0};
            acc = __builtin_amdgcn_mfma_f32_16x16x32_bf16(az10, eb0, acc, 0, 0, 0);
            acc = __builtin_amdgcn_mfma_f32_16x16x32_bf16(az11, eb1, acc, 0, 0, 0);
            acc = __builtin_amdgcn_mfma_f32_16x16x32_bf16(az10, wt0, acc, 0, 0, 0);
            acc = __builtin_amdgcn_mfma_f32_16x16x32_bf16(az11, wt1, acc, 0, 0, 0);
            acc = __builtin_amdgcn_mfma_f32_16x16x32_bf16(az12, wt2, acc, 0, 0, 0);
            const int sb = 16 + kq * 4;
            if (sb + 0 < cnt) out[(size_t)PV1.x * NOUT + n] = acc[0] + H3;
            if (sb + 1 < cnt) out[(size_t)PV1.y * NOUT + n] = acc[1] + H3;
            if (sb + 2 < cnt) out[(size_t)PV1.z * NOUT + n] = acc[2] + H3;
            if (sb + 3 < cnt) out[(size_t)PV1.w * NOUT + n] = acc[3] + H3;
        }
        if (ntiles > 2) {                         // rare (cnt>32): C++ loads
            const unsigned short* xa2 = Xa + ((size_t)(b * 9 + 6)) * 512 + lane * 8;
            const short8 az20 = *(const short8*)(xa2);
            const short8 az21 = *(const short8*)(xa2 + 512);
            const short8 az22 = *(const short8*)(xa2 + 1024);
            const int4 pv2 = *(const int4*)(perm_ws + b * PCAP + 32 + kq * 4);
            f32x4 acc = {0, 0, 0, 0};
            acc = __builtin_amdgcn_mfma_f32_16x16x32_bf16(az20, eb0, acc, 0, 0, 0);
            acc = __builtin_amdgcn_mfma_f32_16x16x32_bf16(az21, eb1, acc, 0, 0, 0);
            acc = __builtin_amdgcn_mfma_f32_16x16x32_bf16(az20, wt0, acc, 0, 0, 0);
            acc = __builtin_amdgcn_mfma_f32_16x16x32_bf16(az21, wt1, acc, 0, 0, 0);
            acc = __builtin_amdgcn_mfma_f32_16x16x32_bf16(az22, wt2, acc, 0, 0, 0);
            const int sb = 32 + kq * 4;
            if (sb + 0 < cnt) out[(size_t)pv2.x * NOUT + n] = acc[0] + H3;
            if (sb + 1 < cnt) out[(size_t)pv2.y * NOUT + n] = acc[1] + H3;
            if (sb + 2 < cnt) out[(size_t)pv2.z * NOUT + n] = acc[2] + H3;
            if (sb + 3 < cnt) out[(size_t)pv2.w * NOUT + n] = acc[3] + H3;
        }
    }
}

// ---------------------------------------------------------------------------
// Softmax: in-place row softmax * size_factor; blocks 0..15 also write
// inverse_dispersion = exp(px_r).
// ---------------------------------------------------------------------------
__global__ __launch_bounds__(256) void k_softmax(
    float*       __restrict__ out,
    const float* __restrict__ sf,
    const float* __restrict__ px_r)
{
    const int c   = blockIdx.x;
    const int tid = threadIdx.x;
    float4* row4 = reinterpret_cast<float4*>(out + (size_t)c * NOUT);

    float4 v[4];
    #pragma unroll
    for (int j = 0; j < 4; ++j) v[j] = row4[j * 256 + tid];

    float m = -3.4e38f;
    #pragma unroll
    for (int j = 0; j < 4; ++j)
        m = fmaxf(fmaxf(fmaxf(m, v[j].x), fmaxf(v[j].y, v[j].z)), v[j].w);

    #pragma unroll
    for (int off = 32; off > 0; off >>= 1)
        m = fmaxf(m, __shfl_xor(m, off, 64));

    __shared__ float s_red[8];
    const int wave = tid >> 6;
    const int lane = tid & 63;
    if (lane == 0) s_red[wave] = m;
    __syncthreads();
    m = fmaxf(fmaxf(s_red[0], s_red[1]), fmaxf(s_red[2], s_red[3]));

    float s = 0.f;
    #pragma unroll
    for (int j = 0; j < 4; ++j) {
        v[j].x = __expf(v[j].x - m); v[j].y = __expf(v[j].y - m);
        v[j].z = __expf(v[j].z - m); v[j].w = __expf(v[j].w - m);
        s += v[j].x + v[j].y + v[j].z + v[j].w;
    }
    #pragma unroll
    for (int off = 32; off > 0; off >>= 1)
        s += __shfl_xor(s, off, 64);
    if (lane == 0) s_red[4 + wave] = s;
    __syncthreads();
    s = s_red[4] + s_red[5] + s_red[6] + s_red[7];

    const float scale = sf[c] / s;
    #pragma unroll
    for (int j = 0; j < 4; ++j) {
        v[j].x *= scale; v[j].y *= scale; v[j].z *= scale; v[j].w *= scale;
        row4[j * 256 + tid] = v[j];
    }

    if (c < NOUT / 256) {                 // 16 blocks cover px_r
        const int i = c * 256 + tid;
        out[(size_t)B_SZ * NOUT + i] = __expf(px_r[i]);
    }
}

// ---------------------------------------------------------------------------
extern "C" void kernel_launch(void* const* d_in, const int* in_sizes, int n_in,
                              void* d_out, int out_size, void* d_ws, size_t ws_size,
                              hipStream_t stream)
{
    const float* z       = (const float*)d_in[0];
    const int*   idx     = (const int*)  d_in[1];
    const float* sf      = (const float*)d_in[2];
    const float* cont    = (const float*)d_in[3];
    const float* amat_W  = (const float*)d_in[4];
    const float* embed_A = (const float*)d_in[5];
    const float* eh3     = (const float*)d_in[6];
    const float* cont_W  = (const float*)d_in[7];
    const float* px_r    = (const float*)d_in[8];
    float* out = (float*)d_out;

    // ws (bytes): cnt[64]@0 | perm[64*48]@256 | Xt bf16 @16384 (196608)
    //             | Wtb bf16 @212992 (786432) | Xa bf16 @999424 (589824)
    char* ws = (char*)d_ws;
    int*            cnt_ws  = (int*)ws;
    int*            perm_ws = (int*)(ws + 256);
    unsigned short* Xt      = (unsigned short*)(ws + 16384);
    unsigned short* Wtb     = (unsigned short*)(ws + 212992);
    unsigned short* Xa      = (unsigned short*)(ws + 999424);

    k_prep<<<WTB_BLOCKS + XT_BLOCKS + 1, 256, 0, stream>>>(
        z, idx, cont, amat_W, cont_W, cnt_ws, perm_ws, Xt, Wtb);

    k_xa<<<144, 256, 0, stream>>>(Xt, perm_ws, Xa);

    dim3 grid1(64, NBATCH);               // 4096 waves x 4 tiles each
    k_gemm<<<grid1, 64, 0, stream>>>(embed_A, eh3, Xa, Wtb,
                                     cnt_ws, perm_ws, out);

    k_softmax<<<B_SZ, 256, 0, stream>>>(out, sf, px_r);
}

// Round 18
// 35.022 us; speedup vs baseline: 1.0729x; 1.0353x over previous
//
#include <hip/hip_runtime.h>
#include <hip/hip_bf16.h>

#define B_SZ   1024
#define NIN    64
#define NOUT   4096
#define NBATCH 64
#define NCONT  16
#define KTOT   96      // z(64) | cont(16) | zero-pad(16)  (logical K)
#define PCAP   48      // per-batch sample capacity (Poisson(16) max ~32)

#define WTB_UNITS  (256 * 3 * 64)             // 49152 16B-units
#define WTB_BLOCKS (WTB_UNITS / 256)          // 192

typedef __attribute__((ext_vector_type(8))) short short8;   // 8 bf16 = 4 VGPR
typedef __attribute__((ext_vector_type(4))) float f32x4;

// f32 -> bf16 bits, round-to-nearest-even
__device__ __forceinline__ short f2bf(float f) {
    unsigned u = __float_as_uint(f);
    return (short)((u + 0x7FFFu + ((u >> 16) & 1u)) >> 16);
}
// pack 8 f32 (two float4) -> short8 bf16 in order
__device__ __forceinline__ short8 pk8(float4 a, float4 b) {
    short8 r;
    r[0]=f2bf(a.x); r[1]=f2bf(a.y); r[2]=f2bf(a.z); r[3]=f2bf(a.w);
    r[4]=f2bf(b.x); r[5]=f2bf(b.y); r[6]=f2bf(b.z); r[7]=f2bf(b.w);
    return r;
}
// K-permutation (applied to BOTH operands -> GEMM invariant)
__device__ __forceinline__ int kpi(int kq, int j) {
    return (j < 4) ? (kq * 4 + j) : (16 + kq * 4 + (j - 4));
}

// ---------------------------------------------------------------------------
// Prep (R17 lesson: k_gemm is near floor; the pipeline overhead is the
// target). Now only Wtb + perm. Xt/Xa eliminated — gemm gathers A-frags
// directly from z/cont.
//   blocks [0,192):  Wtb frag-ordered bf16 (pi-permuted [amat_W;cont_W;0])
//   block  192:      perm/cnt (pad slots pre-zeroed)
// ---------------------------------------------------------------------------
__global__ __launch_bounds__(256) void k_prep(
    const float* __restrict__ z, const int* __restrict__ idx,
    const float* __restrict__ cont, const float* __restrict__ amat_W,
    const float* __restrict__ cont_W,
    int* __restrict__ cnt_ws, int* __restrict__ perm_ws,
    unsigned short* __restrict__ Wtb)
{
    const int bid = blockIdx.x, tid = threadIdx.x;

    if (bid < WTB_BLOCKS) {
        const int u   = bid * 256 + tid;
        const int nt  = u / 192, rem = u - nt * 192;
        const int ks  = rem >> 6, lane = rem & 63;
        const int kq  = lane >> 4, nl = lane & 15;
        const int n   = nt * 16 + nl;
        unsigned short v8[8];
        #pragma unroll
        for (int j = 0; j < 8; ++j) {
            const int k = ks * 32 + kpi(kq, j);
            float v = 0.f;
            if (k < NIN)              v = amat_W[k * NOUT + n];
            else if (k < NIN + NCONT) v = cont_W[(k - NIN) * NOUT + n];
            v8[j] = (unsigned short)f2bf(v);
        }
        *(int4*)(Wtb + (size_t)u * 8) = *(int4*)v8;       // 16B coalesced
    } else {                                  // perm / cnt (one block)
        __shared__ int lcnt[NBATCH];
        if (tid < NBATCH) lcnt[tid] = 0;
        for (int i = tid; i < NBATCH * PCAP; i += 256) perm_ws[i] = 0;
        __syncthreads();
        for (int c = tid; c < B_SZ; c += 256) {
            const int b = idx[c];
            const int p = atomicAdd(&lcnt[b], 1);
            if (p < PCAP) perm_ws[b * PCAP + p] = c;
        }
        __syncthreads();
        if (tid < NBATCH) cnt_ws[tid] = min(lcnt[tid], PCAP);
    }
}

// ---------------------------------------------------------------------------
// Main GEMM — 4 n-tiles per wave; A-frags gathered directly from z/cont in
// the prologue (plain C++ loads, L2-hot, amortized over 4 tiles). The hot
// iteration keeps the R13/R17-proven SELF-CONTAINED asm block (8 loads +
// vmcnt(0) in one block — R15 lesson: in-flight dest regs must never cross
// asm-block boundaries). pi-mapping identical on A and B (Wtb).
// ---------------------------------------------------------------------------
__global__ __launch_bounds__(64) void k_gemm(
    const float* __restrict__ z,
    const float* __restrict__ cont,
    const float* __restrict__ embed_A,
    const float* __restrict__ embed_h3,
    const unsigned short* __restrict__ Wtb,
    const int* __restrict__ cnt_ws,
    const int* __restrict__ perm_ws,
    float* __restrict__ out)
{
    const int lane = threadIdx.x;
    const int nl = lane & 15, kq = lane >> 4;
    const int ib = blockIdx.x;                    // 0..63
    const int b  = blockIdx.y;                    // 0..63
    const int cnt = cnt_ws[b];                    // wave-uniform
    if (cnt == 0) return;
    const int ntiles = (cnt + 15) >> 4;
    const int t0 = ib * 4;                        // first n-tile

    // ---- prologue (C++; compiler-managed waits): indices, store rows, A ----
    const int* pbase = perm_ws + b * PCAP;
    const int c0 = pbase[nl];                     // A-row sample, m-tile 0
    const int c1 = pbase[16 + nl];                // m-tile 1 (pre-zeroed pad)
    const int4 pv0 = *(const int4*)(pbase + kq * 4);
    const int4 pv1 = *(const int4*)(pbase + 16 + kq * 4);

    const float4* z4 = (const float4*)z;          // 16 float4 per sample row
    const float4* q4 = (const float4*)cont;       // 4 float4 per sample row
    const float4 zero4 = {0.f, 0.f, 0.f, 0.f};

    const short8 az00 = pk8(z4[c0 * 16 + kq],      z4[c0 * 16 + 4 + kq]);
    const short8 az01 = pk8(z4[c0 * 16 + 8 + kq],  z4[c0 * 16 + 12 + kq]);
    const short8 az02 = pk8(q4[c0 * 4 + kq],       zero4);
    const short8 az10 = pk8(z4[c1 * 16 + kq],      z4[c1 * 16 + 4 + kq]);
    const short8 az11 = pk8(z4[c1 * 16 + 8 + kq],  z4[c1 * 16 + 12 + kq]);
    const short8 az12 = pk8(q4[c1 * 4 + kq],       zero4);

    const unsigned oe0 = (unsigned)((unsigned)(b * NOUT + t0 * 16 + nl) * 256
                                    + kq * 16);
    const unsigned ow0 = (unsigned)(t0 * 3072 + lane * 16);
    const unsigned oh0 = (unsigned)((b * NOUT + t0 * 16 + nl) * 4);

    #pragma unroll
    for (int it = 0; it < 4; ++it) {
        const unsigned oe = oe0 + (unsigned)(it * 4096);
        const unsigned ow = ow0 + (unsigned)(it * 3072);
        const unsigned oh = oh0 + (unsigned)(it * 64);
        const int n = (t0 + it) * 16 + nl;

        int4 E0, E1, E2, E3, W0, W1, W2;
        float H3;
        asm volatile(
            "global_load_dwordx4 %[e0], %[oe], %[ep]\n\t"
            "global_load_dwordx4 %[e1], %[oe], %[ep] offset:64\n\t"
            "global_load_dwordx4 %[e2], %[oe], %[ep] offset:128\n\t"
            "global_load_dwordx4 %[e3], %[oe], %[ep] offset:192\n\t"
            "global_load_dwordx4 %[w0], %[ow], %[wq]\n\t"
            "global_load_dwordx4 %[w1], %[ow], %[wq] offset:1024\n\t"
            "global_load_dwordx4 %[w2], %[ow], %[wq] offset:2048\n\t"
            "global_load_dword   %[h],  %[oh], %[hp]\n\t"
            "s_waitcnt vmcnt(0)"
            : [e0]"=&v"(E0), [e1]"=&v"(E1), [e2]"=&v"(E2), [e3]"=&v"(E3),
              [w0]"=&v"(W0), [w1]"=&v"(W1), [w2]"=&v"(W2), [h]"=&v"(H3)
            : [oe]"v"(oe), [ow]"v"(ow), [oh]"v"(oh),
              [ep]"s"(embed_A), [wq]"s"(Wtb), [hp]"s"(embed_h3)
            : "memory");
        __builtin_amdgcn_sched_barrier(0);        // rule-#18 fence

        const short8 eb0 = pk8(*(const float4*)&E0, *(const float4*)&E1);
        const short8 eb1 = pk8(*(const float4*)&E2, *(const float4*)&E3);
        const short8 wt0 = *(const short8*)&W0;
        const short8 wt1 = *(const short8*)&W1;
        const short8 wt2 = *(const short8*)&W2;

        {   // m-tile 0
            f32x4 acc = {0, 0, 0, 0};
            acc = __builtin_amdgcn_mfma_f32_16x16x32_bf16(az00, eb0, acc, 0, 0, 0);
            acc = __builtin_amdgcn_mfma_f32_16x16x32_bf16(az01, eb1, acc, 0, 0, 0);
            acc = __builtin_amdgcn_mfma_f32_16x16x32_bf16(az00, wt0, acc, 0, 0, 0);
            acc = __builtin_amdgcn_mfma_f32_16x16x32_bf16(az01, wt1, acc, 0, 0, 0);
            acc = __builtin_amdgcn_mfma_f32_16x16x32_bf16(az02, wt2, acc, 0, 0, 0);
            const int sb = kq * 4;
            if (sb + 0 < cnt) out[(size_t)pv0.x * NOUT + n] = acc[0] + H3;
            if (sb + 1 < cnt) out[(size_t)pv0.y * NOUT + n] = acc[1] + H3;
            if (sb + 2 < cnt) out[(size_t)pv0.z * NOUT + n] = acc[2] + H3;
            if (sb + 3 < cnt) out[(size_t)pv0.w * NOUT + n] = acc[3] + H3;
        }
        if (ntiles > 1) {                         // m-tile 1 (uniform branch)
            f32x4 acc = {0, 0, 0, 0};
            acc = __builtin_amdgcn_mfma_f32_16x16x32_bf16(az10, eb0, acc, 0, 0, 0);
            acc = __builtin_amdgcn_mfma_f32_16x16x32_bf16(az11, eb1, acc, 0, 0, 0);
            acc = __builtin_amdgcn_mfma_f32_16x16x32_bf16(az10, wt0, acc, 0, 0, 0);
            acc = __builtin_amdgcn_mfma_f32_16x16x32_bf16(az11, wt1, acc, 0, 0, 0);
            acc = __builtin_amdgcn_mfma_f32_16x16x32_bf16(az12, wt2, acc, 0, 0, 0);
            const int sb = 16 + kq * 4;
            if (sb + 0 < cnt) out[(size_t)pv1.x * NOUT + n] = acc[0] + H3;
            if (sb + 1 < cnt) out[(size_t)pv1.y * NOUT + n] = acc[1] + H3;
            if (sb + 2 < cnt) out[(size_t)pv1.z * NOUT + n] = acc[2] + H3;
            if (sb + 3 < cnt) out[(size_t)pv1.w * NOUT + n] = acc[3] + H3;
        }
        if (ntiles > 2) {                         // rare (cnt>32): C++ gather
            const int c2 = pbase[32 + nl];
            const int4 pv2 = *(const int4*)(pbase + 32 + kq * 4);
            const short8 az20 = pk8(z4[c2 * 16 + kq],     z4[c2 * 16 + 4 + kq]);
            const short8 az21 = pk8(z4[c2 * 16 + 8 + kq], z4[c2 * 16 + 12 + kq]);
            const short8 az22 = pk8(q4[c2 * 4 + kq],      zero4);
            f32x4 acc = {0, 0, 0, 0};
            acc = __builtin_amdgcn_mfma_f32_16x16x32_bf16(az20, eb0, acc, 0, 0, 0);
            acc = __builtin_amdgcn_mfma_f32_16x16x32_bf16(az21, eb1, acc, 0, 0, 0);
            acc = __builtin_amdgcn_mfma_f32_16x16x32_bf16(az20, wt0, acc, 0, 0, 0);
            acc = __builtin_amdgcn_mfma_f32_16x16x32_bf16(az21, wt1, acc, 0, 0, 0);
            acc = __builtin_amdgcn_mfma_f32_16x16x32_bf16(az22, wt2, acc, 0, 0, 0);
            const int sb = 32 + kq * 4;
            if (sb + 0 < cnt) out[(size_t)pv2.x * NOUT + n] = acc[0] + H3;
            if (sb + 1 < cnt) out[(size_t)pv2.y * NOUT + n] = acc[1] + H3;
            if (sb + 2 < cnt) out[(size_t)pv2.z * NOUT + n] = acc[2] + H3;
            if (sb + 3 < cnt) out[(size_t)pv2.w * NOUT + n] = acc[3] + H3;
        }
    }
}

// ---------------------------------------------------------------------------
// Softmax: in-place row softmax * size_factor; blocks 0..15 also write
// inverse_dispersion = exp(px_r).
// ---------------------------------------------------------------------------
__global__ __launch_bounds__(256) void k_softmax(
    float*       __restrict__ out,
    const float* __restrict__ sf,
    const float* __restrict__ px_r)
{
    const int c   = blockIdx.x;
    const int tid = threadIdx.x;
    float4* row4 = reinterpret_cast<float4*>(out + (size_t)c * NOUT);

    float4 v[4];
    #pragma unroll
    for (int j = 0; j < 4; ++j) v[j] = row4[j * 256 + tid];

    float m = -3.4e38f;
    #pragma unroll
    for (int j = 0; j < 4; ++j)
        m = fmaxf(fmaxf(fmaxf(m, v[j].x), fmaxf(v[j].y, v[j].z)), v[j].w);

    #pragma unroll
    for (int off = 32; off > 0; off >>= 1)
        m = fmaxf(m, __shfl_xor(m, off, 64));

    __shared__ float s_red[8];
    const int wave = tid >> 6;
    const int lane = tid & 63;
    if (lane == 0) s_red[wave] = m;
    __syncthreads();
    m = fmaxf(fmaxf(s_red[0], s_red[1]), fmaxf(s_red[2], s_red[3]));

    float s = 0.f;
    #pragma unroll
    for (int j = 0; j < 4; ++j) {
        v[j].x = __expf(v[j].x - m); v[j].y = __expf(v[j].y - m);
        v[j].z = __expf(v[j].z - m); v[j].w = __expf(v[j].w - m);
        s += v[j].x + v[j].y + v[j].z + v[j].w;
    }
    #pragma unroll
    for (int off = 32; off > 0; off >>= 1)
        s += __shfl_xor(s, off, 64);
    if (lane == 0) s_red[4 + wave] = s;
    __syncthreads();
    s = s_red[4] + s_red[5] + s_red[6] + s_red[7];

    const float scale = sf[c] / s;
    #pragma unroll
    for (int j = 0; j < 4; ++j) {
        v[j].x *= scale; v[j].y *= scale; v[j].z *= scale; v[j].w *= scale;
        row4[j * 256 + tid] = v[j];
    }

    if (c < NOUT / 256) {                 // 16 blocks cover px_r
        const int i = c * 256 + tid;
        out[(size_t)B_SZ * NOUT + i] = __expf(px_r[i]);
    }
}

// ---------------------------------------------------------------------------
extern "C" void kernel_launch(void* const* d_in, const int* in_sizes, int n_in,
                              void* d_out, int out_size, void* d_ws, size_t ws_size,
                              hipStream_t stream)
{
    const float* z       = (const float*)d_in[0];
    const int*   idx     = (const int*)  d_in[1];
    const float* sf      = (const float*)d_in[2];
    const float* cont    = (const float*)d_in[3];
    const float* amat_W  = (const float*)d_in[4];
    const float* embed_A = (const float*)d_in[5];
    const float* eh3     = (const float*)d_in[6];
    const float* cont_W  = (const float*)d_in[7];
    const float* px_r    = (const float*)d_in[8];
    float* out = (float*)d_out;

    // ws (bytes): cnt[64]@0 | perm[64*48]@256 | Wtb bf16 @16384 (786432)
    char* ws = (char*)d_ws;
    int*            cnt_ws  = (int*)ws;
    int*            perm_ws = (int*)(ws + 256);
    unsigned short* Wtb     = (unsigned short*)(ws + 16384);

    k_prep<<<WTB_BLOCKS + 1, 256, 0, stream>>>(
        z, idx, cont, amat_W, cont_W, cnt_ws, perm_ws, Wtb);

    dim3 grid1(64, NBATCH);               // 4096 waves x 4 tiles each
    k_gemm<<<grid1, 64, 0, stream>>>(z, cont, embed_A, eh3, Wtb,
                                     cnt_ws, perm_ws, out);

    k_softmax<<<B_SZ, 256, 0, stream>>>(out, sf, px_r);
}